// Round 2
// baseline (1192.812 us; speedup 1.0000x reference)
//
#include <hip/hip_runtime.h>
#include <hip/hip_bf16.h>

#define D 128
#define O 64

static inline size_t align_up(size_t x, size_t a) { return (x + a - 1) & ~(a - 1); }

// ---------------- setup kernels ----------------

__global__ void init_deg_k(int* __restrict__ deg, int n) {
  int i = blockIdx.x * blockDim.x + threadIdx.x;
  if (i < n) deg[i] = 1;  // self loop
}

__global__ void count_deg_k(const int* __restrict__ col, int* __restrict__ deg, int E, int n) {
  int i = blockIdx.x * blockDim.x + threadIdx.x;
  if (i >= E) return;
  int c = col[i];
  if ((unsigned)c >= (unsigned)n) return;  // skip invalid (defensive)
  atomicAdd(&deg[c], 1);
}

__global__ void dinv_k(const int* __restrict__ deg, float* __restrict__ dinv, int n) {
  int i = blockIdx.x * blockDim.x + threadIdx.x;
  if (i < n) dinv[i] = rsqrtf((float)deg[i]);
}

// exclusive prefix scan of in-degree (deg-1), 3-kernel hierarchical
__global__ void scan1_k(const int* __restrict__ deg, int* __restrict__ row_ptr,
                        int* __restrict__ bsum, int n) {
  __shared__ int s[256];
  int tid = threadIdx.x;
  int gid = blockIdx.x * 256 + tid;
  int v = (gid < n) ? (deg[gid] - 1) : 0;
  s[tid] = v;
  __syncthreads();
  for (int off = 1; off < 256; off <<= 1) {
    int t = (tid >= off) ? s[tid - off] : 0;
    __syncthreads();
    s[tid] += t;
    __syncthreads();
  }
  if (gid < n) row_ptr[gid] = s[tid] - v;  // block-local exclusive
  if (tid == 255) bsum[blockIdx.x] = s[255];
}

__global__ void scan2_k(int* __restrict__ bsum, int nb) {
  // single block; assumes nb <= 512 (N=100k -> nb=391)
  __shared__ int s[512];
  int tid = threadIdx.x;
  int v = (tid < nb) ? bsum[tid] : 0;
  s[tid] = v;
  __syncthreads();
  for (int off = 1; off < 512; off <<= 1) {
    int t = (tid >= off) ? s[tid - off] : 0;
    __syncthreads();
    s[tid] += t;
    __syncthreads();
  }
  if (tid < nb) bsum[tid] = s[tid] - v;  // exclusive
}

__global__ void scan3_k(const int* __restrict__ bsum, const int* __restrict__ deg,
                        int* __restrict__ row_ptr, int* __restrict__ cursor, int n) {
  int gid = blockIdx.x * 256 + threadIdx.x;
  if (gid < n) {
    int r = row_ptr[gid] + bsum[blockIdx.x];
    row_ptr[gid] = r;
    cursor[gid] = r;
    if (gid == n - 1) row_ptr[n] = r + deg[gid] - 1;  // total valid edges
  }
}

__global__ void fill_k(const int* __restrict__ rows, const int* __restrict__ cols,
                       int* __restrict__ cursor, const float* __restrict__ dinv,
                       int* __restrict__ csr_src, float* __restrict__ csr_norm, int E, int n) {
  int i = blockIdx.x * blockDim.x + threadIdx.x;
  if (i >= E) return;
  int u = rows[i], v = cols[i];
  if ((unsigned)v >= (unsigned)n) return;  // must match count_deg_k's skip condition
  if ((unsigned)u >= (unsigned)n) u = 0;   // clamp source only (keeps slots consistent)
  int slot = atomicAdd(&cursor[v], 1);
  csr_src[slot] = u;
  csr_norm[slot] = dinv[u] * dinv[v];
}

__global__ void softmax_k(const float* __restrict__ t, float* __restrict__ tn, int step) {
  int d = threadIdx.x;
  if (d >= D) return;
  float vals[16];
  float m = -1e30f;
  for (int k = 0; k < step; ++k) { vals[k] = t[k * D + d]; m = fmaxf(m, vals[k]); }
  float ssum = 0.f;
  for (int k = 0; k < step; ++k) { vals[k] = expf(vals[k] - m); ssum += vals[k]; }
  float inv = 1.f / ssum;
  for (int k = 0; k < step; ++k) tn[k * D + d] = vals[k] * inv;
}

__global__ void init_hy_k(const float* __restrict__ x, const float* __restrict__ tn,
                          float* __restrict__ h, float* __restrict__ y, int total) {
  int i = blockIdx.x * blockDim.x + threadIdx.x;
  if (i < total) {
    float xv = x[i];
    h[i] = xv;
    y[i] = tn[i & (D - 1)] * xv;
  }
}

// ---------------- hop: pull-based SpMM, one wave per node ----------------

__global__ __launch_bounds__(256) void hop_k(
    const float* __restrict__ h_old, float* __restrict__ h_new, float* __restrict__ y,
    const int* __restrict__ row_ptr, const int* __restrict__ csr_src,
    const float* __restrict__ csr_norm, const float* __restrict__ dinv,
    const float* __restrict__ tk, int n) {
  int wid = (blockIdx.x * blockDim.x + threadIdx.x) >> 6;  // node = wave
  int lane = threadIdx.x & 63;
  if (wid >= n) return;
  int v = wid;
  const float2* h2 = (const float2*)h_old;
  float dv = dinv[v];
  float ns = dv * dv;  // self-loop norm
  float2 hv = h2[(size_t)v * 64 + lane];
  float2 acc;
  acc.x = ns * hv.x;
  acc.y = ns * hv.y;
  int beg = row_ptr[v], end = row_ptr[v + 1];
  for (int i = beg; i < end; ++i) {
    int u = csr_src[i];
    float w = csr_norm[i];
    float2 hu = h2[(size_t)u * 64 + lane];
    acc.x += w * hu.x;
    acc.y += w * hu.y;
  }
  ((float2*)h_new)[(size_t)v * 64 + lane] = acc;
  float2 tk2 = ((const float2*)tk)[lane];
  float2* y2 = (float2*)y;
  float2 yv = y2[(size_t)v * 64 + lane];
  yv.x += tk2.x * acc.x;
  yv.y += tk2.y * acc.y;
  y2[(size_t)v * 64 + lane] = yv;
}

// ---------------- final projection: out = y @ W^T + b ----------------

#define GN 32  // nodes per block

__global__ __launch_bounds__(256) void gemm_k(
    const float* __restrict__ y, const float* __restrict__ W,
    const float* __restrict__ b, float* __restrict__ out, int n) {
  __shared__ float sW[O * 129];  // pad 129 to break bank conflicts across o
  int tid = threadIdx.x;
  for (int i = tid; i < O * D; i += 256) {
    int o = i >> 7, d = i & (D - 1);
    sW[o * 129 + d] = W[i];
  }
  __syncthreads();
  int wv = tid >> 6, lane = tid & 63;
  float bias = b[lane];
  int base = blockIdx.x * GN;
  for (int j = wv; j < GN; j += 4) {
    int v = base + j;
    if (v >= n) continue;
    float2 yv = ((const float2*)y)[(size_t)v * 64 + lane];
    float acc = bias;
#pragma unroll
    for (int dd = 0; dd < 64; ++dd) {
      float ax = __shfl(yv.x, dd, 64);
      float ay = __shfl(yv.y, dd, 64);
      acc += ax * sW[lane * 129 + 2 * dd] + ay * sW[lane * 129 + 2 * dd + 1];
    }
    out[(size_t)v * O + lane] = acc;
  }
}

// ---------------- launch ----------------

extern "C" void kernel_launch(void* const* d_in, const int* in_sizes, int n_in,
                              void* d_out, int out_size, void* d_ws, size_t ws_size,
                              hipStream_t stream) {
  const float* x = (const float*)d_in[0];
  const int* ei = (const int*)d_in[1];
  const float* t = (const float*)d_in[2];
  const float* W = (const float*)d_in[3];
  const float* b = (const float*)d_in[4];
  float* out = (float*)d_out;

  int n = in_sizes[0] / D;
  int E = in_sizes[1] / 2;
  int step = in_sizes[2] / D;
  const int* rows = ei;       // edge_index[0] = sources
  const int* cols = ei + E;   // edge_index[1] = targets

  char* p = (char*)d_ws;
  auto alloc = [&](size_t bytes) { char* r = p; p += align_up(bytes, 256); return r; };
  int*   deg      = (int*)alloc((size_t)n * 4);
  float* dinv     = (float*)alloc((size_t)n * 4);
  int*   row_ptr  = (int*)alloc((size_t)(n + 1) * 4);
  int*   cursor   = (int*)alloc((size_t)n * 4);
  int*   bsum     = (int*)alloc(2048);
  int*   csr_src  = (int*)alloc((size_t)E * 4);
  float* csr_norm = (float*)alloc((size_t)E * 4);
  float* tn       = (float*)alloc((size_t)step * D * 4);
  float* h_a      = (float*)alloc((size_t)n * D * 4);
  float* h_b      = (float*)alloc((size_t)n * D * 4);
  float* y        = (float*)alloc((size_t)n * D * 4);
  // total ~161 MB; ws re-poisoned each call, everything is (re)initialized below

  int nb1 = (n + 255) / 256;
  init_deg_k<<<nb1, 256, 0, stream>>>(deg, n);
  count_deg_k<<<(E + 255) / 256, 256, 0, stream>>>(cols, deg, E, n);
  dinv_k<<<nb1, 256, 0, stream>>>(deg, dinv, n);
  scan1_k<<<nb1, 256, 0, stream>>>(deg, row_ptr, bsum, n);
  scan2_k<<<1, 512, 0, stream>>>(bsum, nb1);
  scan3_k<<<nb1, 256, 0, stream>>>(bsum, deg, row_ptr, cursor, n);
  fill_k<<<(E + 255) / 256, 256, 0, stream>>>(rows, cols, cursor, dinv, csr_src, csr_norm, E, n);
  softmax_k<<<1, 128, 0, stream>>>(t, tn, step);
  init_hy_k<<<((size_t)n * D + 255) / 256, 256, 0, stream>>>(x, tn, h_a, y, n * D);

  float* ho = h_a;
  float* hn = h_b;
  for (int k = 1; k < step; ++k) {
    hop_k<<<(n + 3) / 4, 256, 0, stream>>>(ho, hn, y, row_ptr, csr_src, csr_norm, dinv,
                                           tn + (size_t)k * D, n);
    float* tmp = ho; ho = hn; hn = tmp;
  }

  gemm_k<<<(n + GN - 1) / GN, 256, 0, stream>>>(y, W, b, out, n);
}

// Round 3
// 892.478 us; speedup vs baseline: 1.3365x; 1.3365x over previous
//
#include <hip/hip_runtime.h>

typedef _Float16 half2_t __attribute__((ext_vector_type(2)));
typedef unsigned int uint;

#define D 128
#define O 64

static inline size_t align_up(size_t x, size_t a) { return (x + a - 1) & ~(a - 1); }

// ---------------- setup kernels ----------------

__global__ void init_deg_k(int* __restrict__ deg, int n) {
  int i = blockIdx.x * blockDim.x + threadIdx.x;
  if (i < n) deg[i] = 1;  // self loop
}

__global__ void count_deg_k(const int* __restrict__ col, int* __restrict__ deg, int E, int n) {
  int i = blockIdx.x * blockDim.x + threadIdx.x;
  if (i >= E) return;
  int c = col[i];
  if ((unsigned)c >= (unsigned)n) return;
  atomicAdd(&deg[c], 1);
}

__global__ void dinv_k(const int* __restrict__ deg, float* __restrict__ dinv, int n) {
  int i = blockIdx.x * blockDim.x + threadIdx.x;
  if (i < n) dinv[i] = rsqrtf((float)deg[i]);
}

__global__ void scan1_k(const int* __restrict__ deg, int* __restrict__ row_ptr,
                        int* __restrict__ bsum, int n) {
  __shared__ int s[256];
  int tid = threadIdx.x;
  int gid = blockIdx.x * 256 + tid;
  int v = (gid < n) ? (deg[gid] - 1) : 0;
  s[tid] = v;
  __syncthreads();
  for (int off = 1; off < 256; off <<= 1) {
    int t = (tid >= off) ? s[tid - off] : 0;
    __syncthreads();
    s[tid] += t;
    __syncthreads();
  }
  if (gid < n) row_ptr[gid] = s[tid] - v;
  if (tid == 255) bsum[blockIdx.x] = s[255];
}

__global__ void scan2_k(int* __restrict__ bsum, int nb) {
  // single block; nb <= 512 (N=100k -> nb=391)
  __shared__ int s[512];
  int tid = threadIdx.x;
  int v = (tid < nb) ? bsum[tid] : 0;
  s[tid] = v;
  __syncthreads();
  for (int off = 1; off < 512; off <<= 1) {
    int t = (tid >= off) ? s[tid - off] : 0;
    __syncthreads();
    s[tid] += t;
    __syncthreads();
  }
  if (tid < nb) bsum[tid] = s[tid] - v;
}

__global__ void scan3_k(const int* __restrict__ bsum, const int* __restrict__ deg,
                        int* __restrict__ row_ptr, int* __restrict__ cursor, int n) {
  int gid = blockIdx.x * 256 + threadIdx.x;
  if (gid < n) {
    int r = row_ptr[gid] + bsum[blockIdx.x];
    row_ptr[gid] = r;
    cursor[gid] = r;
    if (gid == n - 1) row_ptr[n] = r + deg[gid] - 1;
  }
}

__global__ void fill_k(const int* __restrict__ rows, const int* __restrict__ cols,
                       int* __restrict__ cursor, const float* __restrict__ dinv,
                       int* __restrict__ csr_src, float* __restrict__ csr_norm, int E, int n) {
  int i = blockIdx.x * blockDim.x + threadIdx.x;
  if (i >= E) return;
  int u = rows[i], v = cols[i];
  if ((unsigned)v >= (unsigned)n) return;
  if ((unsigned)u >= (unsigned)n) u = 0;
  int slot = atomicAdd(&cursor[v], 1);
  csr_src[slot] = u;
  csr_norm[slot] = dinv[u] * dinv[v];
}

__global__ void softmax_k(const float* __restrict__ t, float* __restrict__ tn, int step) {
  int d = threadIdx.x;
  if (d >= D) return;
  float vals[16];
  float m = -1e30f;
  for (int k = 0; k < step; ++k) { vals[k] = t[k * D + d]; m = fmaxf(m, vals[k]); }
  float ssum = 0.f;
  for (int k = 0; k < step; ++k) { vals[k] = expf(vals[k] - m); ssum += vals[k]; }
  float inv = 1.f / ssum;
  for (int k = 0; k < step; ++k) tn[k * D + d] = vals[k] * inv;
}

__global__ void pack_w_k(const float* __restrict__ W, uint* __restrict__ Wpk, int total) {
  int i = blockIdx.x * blockDim.x + threadIdx.x;  // total = O*64, i = o*64+dd
  if (i >= total) return;
  int o = i >> 6, dd = i & 63;
  half2_t h;
  h.x = (_Float16)W[o * D + 2 * dd];
  h.y = (_Float16)W[o * D + 2 * dd + 1];
  Wpk[i] = *(uint*)&h;
}

__global__ void init_h_k(const float* __restrict__ x, half2_t* __restrict__ h0, int total) {
  int i = blockIdx.x * blockDim.x + threadIdx.x;  // total = N*64 pairs
  if (i >= total) return;
  float2 v = ((const float2*)x)[i];
  half2_t o;
  o.x = (_Float16)v.x;
  o.y = (_Float16)v.y;
  h0[i] = o;
}

// ---------------- hop: pull-based SpMM, one wave per node ----------------
// DO_Y: 0 = no y update; 1 = y  = t_prev*h_old + t_cur*h_new;
//       2 = y += t_prev*h_old + t_cur*h_new
template <int DO_Y>
__global__ __launch_bounds__(256) void hop_k(
    const half2_t* __restrict__ h_old, half2_t* __restrict__ h_new, half2_t* __restrict__ y,
    const int* __restrict__ row_ptr, const int* __restrict__ csr_src,
    const float* __restrict__ csr_norm, const float* __restrict__ dinv,
    const float* __restrict__ tprev, const float* __restrict__ tcur, int n) {
  int wid = (blockIdx.x * blockDim.x + threadIdx.x) >> 6;  // node = wave
  int lane = threadIdx.x & 63;
  if (wid >= n) return;
  int v = wid;
  float dv = dinv[v];
  float ns = dv * dv;  // self-loop norm
  half2_t hv = h_old[(size_t)v * 64 + lane];
  float hx = (float)hv.x, hy = (float)hv.y;
  float ax = ns * hx, ay = ns * hy;
  int beg = row_ptr[v], end = row_ptr[v + 1];
  for (int i = beg; i < end; ++i) {
    int u = csr_src[i];       // wave-uniform -> scalar load
    float w = csr_norm[i];    // wave-uniform -> scalar load
    half2_t hu = h_old[(size_t)u * 64 + lane];  // 256B coalesced wave gather
    ax += w * (float)hu.x;
    ay += w * (float)hu.y;
  }
  half2_t hn;
  hn.x = (_Float16)ax;
  hn.y = (_Float16)ay;
  h_new[(size_t)v * 64 + lane] = hn;
  if (DO_Y) {
    float2 ta = ((const float2*)tprev)[lane];
    float2 tb = ((const float2*)tcur)[lane];
    float yx = ta.x * hx + tb.x * ax;
    float yy = ta.y * hy + tb.y * ay;
    if (DO_Y == 2) {
      half2_t yo = y[(size_t)v * 64 + lane];
      yx += (float)yo.x;
      yy += (float)yo.y;
    }
    half2_t yn;
    yn.x = (_Float16)yx;
    yn.y = (_Float16)yy;
    y[(size_t)v * 64 + lane] = yn;
  }
}

// ---------------- final projection: out = y @ W^T + b ----------------
// lane = output channel o; W row resident in 64 VGPRs (f16x2);
// y row loaded wave-uniformly (scalar path); inner loop = v_dot2_f32_f16.
__global__ __launch_bounds__(256) void proj_k(
    const uint* __restrict__ y, const uint* __restrict__ Wpk,
    const float* __restrict__ b, float* __restrict__ out, int n, int nwaves) {
  int lane = threadIdx.x & 63;
  int wid = (blockIdx.x * blockDim.x + threadIdx.x) >> 6;
  uint wreg[64];
  const uint* wp = Wpk + lane * 64;
#pragma unroll
  for (int j = 0; j < 64; ++j) wreg[j] = wp[j];
  float bias = b[lane];
  for (int v = wid; v < n; v += nwaves) {
    int vu = __builtin_amdgcn_readfirstlane(v);
    const uint* yrow = y + (size_t)vu * 64;
    float acc = bias;
#pragma unroll
    for (int dd = 0; dd < 64; ++dd) {
      uint yv = yrow[dd];
#if defined(__has_builtin) && __has_builtin(__builtin_amdgcn_fdot2)
      acc = __builtin_amdgcn_fdot2(*(half2_t*)&yv, *(half2_t*)&wreg[dd], acc, false);
#else
      half2_t yh = *(half2_t*)&yv, wh = *(half2_t*)&wreg[dd];
      acc += (float)yh.x * (float)wh.x + (float)yh.y * (float)wh.y;
#endif
    }
    out[(size_t)vu * O + lane] = acc;
  }
}

// ---------------- launch ----------------

extern "C" void kernel_launch(void* const* d_in, const int* in_sizes, int n_in,
                              void* d_out, int out_size, void* d_ws, size_t ws_size,
                              hipStream_t stream) {
  const float* x = (const float*)d_in[0];
  const int* ei = (const int*)d_in[1];
  const float* t = (const float*)d_in[2];
  const float* W = (const float*)d_in[3];
  const float* b = (const float*)d_in[4];
  float* out = (float*)d_out;

  int n = in_sizes[0] / D;
  int E = in_sizes[1] / 2;
  int step = in_sizes[2] / D;  // = 10
  const int* rows = ei;        // sources
  const int* cols = ei + E;    // targets

  char* p = (char*)d_ws;
  auto alloc = [&](size_t bytes) { char* r = p; p += align_up(bytes, 256); return r; };
  int*     deg      = (int*)alloc((size_t)n * 4);
  float*   dinv     = (float*)alloc((size_t)n * 4);
  int*     row_ptr  = (int*)alloc((size_t)(n + 1) * 4);
  int*     cursor   = (int*)alloc((size_t)n * 4);
  int*     bsum     = (int*)alloc(2048);
  int*     csr_src  = (int*)alloc((size_t)E * 4);
  float*   csr_norm = (float*)alloc((size_t)E * 4);
  float*   tn       = (float*)alloc((size_t)step * D * 4);
  uint*    Wpk      = (uint*)alloc((size_t)O * 64 * 4);
  half2_t* h_a      = (half2_t*)alloc((size_t)n * 64 * 4);
  half2_t* h_b      = (half2_t*)alloc((size_t)n * 64 * 4);
  half2_t* y        = (half2_t*)alloc((size_t)n * 64 * 4);
  // total ~84 MB — fits Infinity Cache alongside CSR

  int nb1 = (n + 255) / 256;
  init_deg_k<<<nb1, 256, 0, stream>>>(deg, n);
  count_deg_k<<<(E + 255) / 256, 256, 0, stream>>>(cols, deg, E, n);
  dinv_k<<<nb1, 256, 0, stream>>>(deg, dinv, n);
  scan1_k<<<nb1, 256, 0, stream>>>(deg, row_ptr, bsum, n);
  scan2_k<<<1, 512, 0, stream>>>(bsum, nb1);
  scan3_k<<<nb1, 256, 0, stream>>>(bsum, deg, row_ptr, cursor, n);
  fill_k<<<(E + 255) / 256, 256, 0, stream>>>(rows, cols, cursor, dinv, csr_src, csr_norm, E, n);
  softmax_k<<<1, 128, 0, stream>>>(t, tn, step);
  pack_w_k<<<(O * 64 + 255) / 256, 256, 0, stream>>>(W, Wpk, O * 64);
  init_h_k<<<((size_t)n * 64 + 255) / 256, 256, 0, stream>>>(x, h_a, n * 64);

  half2_t* ho = h_a;
  half2_t* hn = h_b;
  int hop_blocks = (n + 3) / 4;
  for (int k = 1; k < step; ++k) {
    const float* tp = tn + (size_t)(k - 1) * D;
    const float* tc = tn + (size_t)k * D;
    if (k & 1) {
      if (k == 1)
        hop_k<1><<<hop_blocks, 256, 0, stream>>>(ho, hn, y, row_ptr, csr_src, csr_norm, dinv, tp, tc, n);
      else
        hop_k<2><<<hop_blocks, 256, 0, stream>>>(ho, hn, y, row_ptr, csr_src, csr_norm, dinv, tp, tc, n);
    } else {
      hop_k<0><<<hop_blocks, 256, 0, stream>>>(ho, hn, y, row_ptr, csr_src, csr_norm, dinv, tp, tc, n);
    }
    half2_t* tmp = ho; ho = hn; hn = tmp;
  }
  // step=10: odd hops k=1,3,5,7,9 cover t0..t9 exactly

  int proj_blocks = 512;
  int nwaves = proj_blocks * 4;
  proj_k<<<proj_blocks, 256, 0, stream>>>((const uint*)y, Wpk, b, out, n, nwaves);
}

// Round 4
// 586.409 us; speedup vs baseline: 2.0341x; 1.5219x over previous
//
#include <hip/hip_runtime.h>

typedef _Float16 half2_t __attribute__((ext_vector_type(2)));
typedef unsigned int uint;

#define D 128
#define O 64

static inline size_t align_up(size_t x, size_t a) { return (x + a - 1) & ~(a - 1); }

// ---------------- setup kernels ----------------

__global__ void init_deg_k(int* __restrict__ deg, int n) {
  int i = blockIdx.x * blockDim.x + threadIdx.x;
  if (i < n) deg[i] = 1;  // self loop
}

__global__ void count_deg_k(const int* __restrict__ col, int* __restrict__ deg, int E, int n) {
  int i = blockIdx.x * blockDim.x + threadIdx.x;
  if (i >= E) return;
  int c = col[i];
  if ((unsigned)c >= (unsigned)n) return;
  atomicAdd(&deg[c], 1);
}

__global__ void dinv_k(const int* __restrict__ deg, float* __restrict__ dinv, int n) {
  int i = blockIdx.x * blockDim.x + threadIdx.x;
  if (i < n) dinv[i] = rsqrtf((float)deg[i]);
}

__global__ void scan1_k(const int* __restrict__ deg, int* __restrict__ row_ptr,
                        int* __restrict__ bsum, int n) {
  __shared__ int s[256];
  int tid = threadIdx.x;
  int gid = blockIdx.x * 256 + tid;
  int v = (gid < n) ? (deg[gid] - 1) : 0;
  s[tid] = v;
  __syncthreads();
  for (int off = 1; off < 256; off <<= 1) {
    int t = (tid >= off) ? s[tid - off] : 0;
    __syncthreads();
    s[tid] += t;
    __syncthreads();
  }
  if (gid < n) row_ptr[gid] = s[tid] - v;
  if (tid == 255) bsum[blockIdx.x] = s[255];
}

__global__ void scan2_k(int* __restrict__ bsum, int nb) {
  // single block; nb <= 512 (N=100k -> nb=391)
  __shared__ int s[512];
  int tid = threadIdx.x;
  int v = (tid < nb) ? bsum[tid] : 0;
  s[tid] = v;
  __syncthreads();
  for (int off = 1; off < 512; off <<= 1) {
    int t = (tid >= off) ? s[tid - off] : 0;
    __syncthreads();
    s[tid] += t;
    __syncthreads();
  }
  if (tid < nb) bsum[tid] = s[tid] - v;
}

__global__ void scan3_k(const int* __restrict__ bsum, const int* __restrict__ deg,
                        int* __restrict__ row_ptr, int* __restrict__ cursor, int n) {
  int gid = blockIdx.x * 256 + threadIdx.x;
  if (gid < n) {
    int r = row_ptr[gid] + bsum[blockIdx.x];
    row_ptr[gid] = r;
    cursor[gid] = r;
    if (gid == n - 1) row_ptr[n] = r + deg[gid] - 1;
  }
}

__global__ void fill_k(const int* __restrict__ rows, const int* __restrict__ cols,
                       int* __restrict__ cursor, const float* __restrict__ dinv,
                       int* __restrict__ csr_src, float* __restrict__ csr_norm, int E, int n) {
  int i = blockIdx.x * blockDim.x + threadIdx.x;
  if (i >= E) return;
  int u = rows[i], v = cols[i];
  if ((unsigned)v >= (unsigned)n) return;
  if ((unsigned)u >= (unsigned)n) u = 0;
  int slot = atomicAdd(&cursor[v], 1);
  csr_src[slot] = u;
  csr_norm[slot] = dinv[u] * dinv[v];
}

__global__ void softmax_k(const float* __restrict__ t, float* __restrict__ tn, int step) {
  int d = threadIdx.x;
  if (d >= D) return;
  float vals[16];
  float m = -1e30f;
  for (int k = 0; k < step; ++k) { vals[k] = t[k * D + d]; m = fmaxf(m, vals[k]); }
  float ssum = 0.f;
  for (int k = 0; k < step; ++k) { vals[k] = expf(vals[k] - m); ssum += vals[k]; }
  float inv = 1.f / ssum;
  for (int k = 0; k < step; ++k) tn[k * D + d] = vals[k] * inv;
}

__global__ void pack_w_k(const float* __restrict__ W, uint* __restrict__ Wpk, int total) {
  int i = blockIdx.x * blockDim.x + threadIdx.x;  // total = O*64, i = o*64+dd
  if (i >= total) return;
  int o = i >> 6, dd = i & 63;
  half2_t h;
  h.x = (_Float16)W[o * D + 2 * dd];
  h.y = (_Float16)W[o * D + 2 * dd + 1];
  Wpk[i] = *(uint*)&h;
}

__global__ void init_h_k(const float* __restrict__ x, half2_t* __restrict__ h0, int total) {
  int i = blockIdx.x * blockDim.x + threadIdx.x;  // total = N*64 pairs
  if (i >= total) return;
  float2 v = ((const float2*)x)[i];
  half2_t o;
  o.x = (_Float16)v.x;
  o.y = (_Float16)v.y;
  h0[i] = o;
}

// ---------------- hop: pull-based SpMM, one wave per node ----------------
// 8-wide software-pipelined gather: load 8 CSR idx/weights (wave-uniform,
// scalar path), then 8 independent 256B gathers, then FMA. Tail clamped.
// DO_Y: 0 = no y update; 1 = y  = t_prev*h_old + t_cur*h_new;
//       2 = y += t_prev*h_old + t_cur*h_new
#define UNR 8
template <int DO_Y>
__global__ __launch_bounds__(256) void hop_k(
    const half2_t* __restrict__ h_old, half2_t* __restrict__ h_new, half2_t* __restrict__ y,
    const int* __restrict__ row_ptr, const int* __restrict__ csr_src,
    const float* __restrict__ csr_norm, const float* __restrict__ dinv,
    const float* __restrict__ tprev, const float* __restrict__ tcur, int n) {
  int wid = (blockIdx.x * blockDim.x + threadIdx.x) >> 6;
  int lane = threadIdx.x & 63;
  if (wid >= n) return;
  int v = __builtin_amdgcn_readfirstlane(wid);  // wave-uniform node id -> SGPR
  float dv = dinv[v];
  float ns = dv * dv;  // self-loop norm
  half2_t hv = h_old[(size_t)v * 64 + lane];
  float hx = (float)hv.x, hy = (float)hv.y;
  float ax = ns * hx, ay = ns * hy;
  int beg = __builtin_amdgcn_readfirstlane(row_ptr[v]);
  int end = __builtin_amdgcn_readfirstlane(row_ptr[v + 1]);
  for (int i = beg; i < end; i += UNR) {
    int u[UNR];
    float w[UNR];
#pragma unroll
    for (int j = 0; j < UNR; ++j) {
      int ic = i + j;
      int icl = (ic < end - 1) ? ic : (end - 1);  // clamp (end>beg>=0 here)
      u[j] = csr_src[icl];
      float wj = csr_norm[icl];
      w[j] = (ic < end) ? wj : 0.f;
    }
    half2_t g[UNR];
#pragma unroll
    for (int j = 0; j < UNR; ++j) g[j] = h_old[(size_t)u[j] * 64 + lane];
#pragma unroll
    for (int j = 0; j < UNR; ++j) {
      ax += w[j] * (float)g[j].x;
      ay += w[j] * (float)g[j].y;
    }
  }
  half2_t hn;
  hn.x = (_Float16)ax;
  hn.y = (_Float16)ay;
  h_new[(size_t)v * 64 + lane] = hn;
  if (DO_Y) {
    float2 ta = ((const float2*)tprev)[lane];
    float2 tb = ((const float2*)tcur)[lane];
    float yx = ta.x * hx + tb.x * ax;
    float yy = ta.y * hy + tb.y * ay;
    if (DO_Y == 2) {
      half2_t yo = y[(size_t)v * 64 + lane];
      yx += (float)yo.x;
      yy += (float)yo.y;
    }
    half2_t yn;
    yn.x = (_Float16)yx;
    yn.y = (_Float16)yy;
    y[(size_t)v * 64 + lane] = yn;
  }
}

// ---------------- final projection: out = y @ W^T + b ----------------

__global__ __launch_bounds__(256) void proj_k(
    const uint* __restrict__ y, const uint* __restrict__ Wpk,
    const float* __restrict__ b, float* __restrict__ out, int n, int nwaves) {
  int lane = threadIdx.x & 63;
  int wid = (blockIdx.x * blockDim.x + threadIdx.x) >> 6;
  uint wreg[64];
  const uint* wp = Wpk + lane * 64;
#pragma unroll
  for (int j = 0; j < 64; ++j) wreg[j] = wp[j];
  float bias = b[lane];
  for (int v = wid; v < n; v += nwaves) {
    int vu = __builtin_amdgcn_readfirstlane(v);
    const uint* yrow = y + (size_t)vu * 64;
    float acc = bias;
#pragma unroll
    for (int dd = 0; dd < 64; ++dd) {
      uint yv = yrow[dd];
#if defined(__has_builtin) && __has_builtin(__builtin_amdgcn_fdot2)
      acc = __builtin_amdgcn_fdot2(*(half2_t*)&yv, *(half2_t*)&wreg[dd], acc, false);
#else
      half2_t yh = *(half2_t*)&yv, wh = *(half2_t*)&wreg[dd];
      acc += (float)yh.x * (float)wh.x + (float)yh.y * (float)wh.y;
#endif
    }
    out[(size_t)vu * O + lane] = acc;
  }
}

// ---------------- launch ----------------

extern "C" void kernel_launch(void* const* d_in, const int* in_sizes, int n_in,
                              void* d_out, int out_size, void* d_ws, size_t ws_size,
                              hipStream_t stream) {
  const float* x = (const float*)d_in[0];
  const int* ei = (const int*)d_in[1];
  const float* t = (const float*)d_in[2];
  const float* W = (const float*)d_in[3];
  const float* b = (const float*)d_in[4];
  float* out = (float*)d_out;

  int n = in_sizes[0] / D;
  int E = in_sizes[1] / 2;
  int step = in_sizes[2] / D;  // = 10
  const int* rows = ei;        // sources
  const int* cols = ei + E;    // targets

  char* p = (char*)d_ws;
  auto alloc = [&](size_t bytes) { char* r = p; p += align_up(bytes, 256); return r; };
  int*     deg      = (int*)alloc((size_t)n * 4);
  float*   dinv     = (float*)alloc((size_t)n * 4);
  int*     row_ptr  = (int*)alloc((size_t)(n + 1) * 4);
  int*     cursor   = (int*)alloc((size_t)n * 4);
  int*     bsum     = (int*)alloc(2048);
  int*     csr_src  = (int*)alloc((size_t)E * 4);
  float*   csr_norm = (float*)alloc((size_t)E * 4);
  float*   tn       = (float*)alloc((size_t)step * D * 4);
  uint*    Wpk      = (uint*)alloc((size_t)O * 64 * 4);
  half2_t* h_a      = (half2_t*)alloc((size_t)n * 64 * 4);
  half2_t* h_b      = (half2_t*)alloc((size_t)n * 64 * 4);
  half2_t* y        = (half2_t*)alloc((size_t)n * 64 * 4);

  int nb1 = (n + 255) / 256;
  init_deg_k<<<nb1, 256, 0, stream>>>(deg, n);
  count_deg_k<<<(E + 255) / 256, 256, 0, stream>>>(cols, deg, E, n);
  dinv_k<<<nb1, 256, 0, stream>>>(deg, dinv, n);
  scan1_k<<<nb1, 256, 0, stream>>>(deg, row_ptr, bsum, n);
  scan2_k<<<1, 512, 0, stream>>>(bsum, nb1);
  scan3_k<<<nb1, 256, 0, stream>>>(bsum, deg, row_ptr, cursor, n);
  fill_k<<<(E + 255) / 256, 256, 0, stream>>>(rows, cols, cursor, dinv, csr_src, csr_norm, E, n);
  softmax_k<<<1, 128, 0, stream>>>(t, tn, step);
  pack_w_k<<<(O * 64 + 255) / 256, 256, 0, stream>>>(W, Wpk, O * 64);
  init_h_k<<<((size_t)n * 64 + 255) / 256, 256, 0, stream>>>(x, h_a, n * 64);

  half2_t* ho = h_a;
  half2_t* hn = h_b;
  int hop_blocks = (n + 3) / 4;
  for (int k = 1; k < step; ++k) {
    const float* tp = tn + (size_t)(k - 1) * D;
    const float* tc = tn + (size_t)k * D;
    if (k & 1) {
      if (k == 1)
        hop_k<1><<<hop_blocks, 256, 0, stream>>>(ho, hn, y, row_ptr, csr_src, csr_norm, dinv, tp, tc, n);
      else
        hop_k<2><<<hop_blocks, 256, 0, stream>>>(ho, hn, y, row_ptr, csr_src, csr_norm, dinv, tp, tc, n);
    } else {
      hop_k<0><<<hop_blocks, 256, 0, stream>>>(ho, hn, y, row_ptr, csr_src, csr_norm, dinv, tp, tc, n);
    }
    half2_t* tmp = ho; ho = hn; hn = tmp;
  }
  // step=10: odd hops k=1,3,5,7,9 cover t0..t9 exactly

  int proj_blocks = 512;
  int nwaves = proj_blocks * 4;
  proj_k<<<proj_blocks, 256, 0, stream>>>((const uint*)y, Wpk, b, out, n, nwaves);
}